// Round 6
// baseline (154.703 us; speedup 1.0000x reference)
//
#include <hip/hip_runtime.h>
#include <math.h>

#define BB 8
#define NA 5
#define NC 8
#define NH 192
#define NW 192
#define TT 50
#define ATTRS 15
#define THRESH_F 0.6f

#define NTGT (BB * TT)                 // 400
#define PLANE (NH * NW)                // 36864
#define BATCH_CELLS (NA * PLANE)       // 184320
#define NCELLS (BB * BATCH_CELLS)      // 1474560
#define HSZ 4096
#define HEMPTY 0xFFFFFFFFu

// ws layout: acc[0..15] doubles @0, ticket u32 @128, partials @192
// acc: 0 n_obj, 1 sx, 2 sy, 3 sw, 4 sh, 5 bce_obj, 6 ce, 7 excl_bce, 8 excl_cnt
#define TICK_OFF 128
#define PART_OFF 192
#define CONF_BLOCKS 360
#define CONF_THREADS 256
#define CONF_TOTAL (CONF_BLOCKS * CONF_THREADS)   // 92160; N4 = 368640 = 4*92160

struct Rec {
    int cell;      // (a*NH + gj)*NW + gi  (within batch)
    int label;
    float tx, ty, tw, th;
    int valid;
    int pad;
};

__device__ __forceinline__ float sigmoidf_(float v) {
    return 1.0f / (1.0f + expf(-v));
}

__device__ __forceinline__ float noobj_term(float v) {
    float p = fminf(fmaxf(sigmoidf_(v), 1e-7f), 1.0f - 1e-7f);
    return -log1pf(-p);
}

// ---------------------------------------------------------------------------
// Kernel A: single block, 512 threads.
//  - zero the ticket
//  - per-target build (Rec in LDS) + LDS hash-set dedup of excluded cells;
//    each NEW cell contributes its noobj-bce term to the correction accs
//  - per-surviving-target losses, 9-value block reduction -> acc[]
// ---------------------------------------------------------------------------
__global__ __launch_bounds__(512) void build_obj_k(const float* __restrict__ x,
                                                   const float* __restrict__ tgt,
                                                   const float* __restrict__ anchors,
                                                   double* __restrict__ acc,
                                                   unsigned int* __restrict__ ticket) {
    __shared__ Rec srecs[NTGT];
    __shared__ unsigned int hset[HSZ];
    __shared__ double wsum[8][9];
    const int tid = threadIdx.x;

    for (int i = tid; i < HSZ; i += 512) hset[i] = HEMPTY;
    if (tid == 0) *ticket = 0u;
    __syncthreads();

    double corr_b = 0.0, corr_c = 0.0;

    // ---- phase 1: build + excluded-set dedup ----
    if (tid < NTGT) {
        const int b = tid / TT;
        const float* p = tgt + (size_t)tid * 5;
        float lab = p[0], cx = p[1], cy = p[2], cw = p[3], ch = p[4];
        int valid = ((lab + cx + cy + cw + ch) != 0.0f) ? 1 : 0;
        float gx = cx * NW, gy = cy * NH, gw = cw * NW, gh = ch * NH;
        int gi = min(max((int)floorf(gx), 0), NW - 1);
        int gj = min(max((int)floorf(gy), 0), NH - 1);
        float ious[NA];
        float aw[NA], ah[NA];
        int best = 0; float bi = -1.0f;
        #pragma unroll
        for (int a = 0; a < NA; ++a) {
            aw[a] = anchors[2 * a];
            ah[a] = anchors[2 * a + 1];
            float inter = fminf(gw, aw[a]) * fminf(gh, ah[a]);
            float un = gw * gh + aw[a] * ah[a] - inter;
            float iou = inter / un;
            ious[a] = iou;
            if (iou > bi) { bi = iou; best = a; }   // first-max (jnp.argmax)
        }
        if (valid) {
            // excluded set = {iou>thresh cells} U {best cell}
            #pragma unroll
            for (int a = 0; a <= NA; ++a) {
                int aa; bool doit;
                if (a < NA) { aa = a; doit = (ious[a] > THRESH_F); }
                else        { aa = best; doit = true; }
                if (!doit) continue;
                unsigned int key = (unsigned int)((b * NA + aa) * PLANE + gj * NW + gi);
                unsigned int h = (key * 2654435761u) & (HSZ - 1);
                while (true) {
                    unsigned int old = atomicCAS(&hset[h], HEMPTY, key);
                    if (old == HEMPTY) {   // new cell -> contribute correction
                        int cb = key / BATCH_CELLS;
                        int cr = key % BATCH_CELLS;
                        int ca = cr / PLANE;
                        int chw = cr % PLANE;
                        float v = x[((size_t)(cb * NA + ca) * ATTRS + 6) * PLANE + chw];
                        corr_b += (double)noobj_term(v);
                        corr_c += 1.0;
                        break;
                    }
                    if (old == key) break;  // duplicate
                    h = (h + 1) & (HSZ - 1);
                }
            }
        }
        Rec r;
        r.valid = valid;
        r.cell = (best * NH + gj) * NW + gi;
        r.label = (int)lab;
        r.tx = gx - floorf(gx);
        r.ty = gy - floorf(gy);
        r.tw = logf(gw / aw[best] + 1e-16f);
        r.th = logf(gh / ah[best] + 1e-16f);
        srecs[tid] = r;
    }
    __syncthreads();

    // ---- phase 2: per-object losses ----
    double v[9];
    #pragma unroll
    for (int k = 0; k < 9; ++k) v[k] = 0.0;
    v[7] = corr_b;
    v[8] = corr_c;

    if (tid < NTGT) {
        Rec r = srecs[tid];
        if (r.valid) {
            const int b = tid / TT, t = tid % TT;
            bool superseded = false;
            for (int t2 = t + 1; t2 < TT; ++t2) {
                Rec r2 = srecs[b * TT + t2];
                if (r2.valid && r2.cell == r.cell) { superseded = true; break; }
            }
            if (!superseded) {
                int a  = r.cell / PLANE;
                int hw = r.cell % PLANE;
                size_t base = ((size_t)(b * NA + a) * ATTRS) * PLANE + hw;
                float v0 = x[base + 0 * PLANE];
                float v1 = x[base + 1 * PLANE];
                float v2 = x[base + 2 * PLANE];
                float v3 = x[base + 3 * PLANE];
                float v6 = x[base + 6 * PLANE];
                float px = sigmoidf_(v0);
                float py = sigmoidf_(v1);
                float pconf = fminf(fmaxf(sigmoidf_(v6), 1e-7f), 1.0f - 1e-7f);
                float c[NC];
                float m = -INFINITY;
                #pragma unroll
                for (int k = 0; k < NC; ++k) {
                    float sv = sigmoidf_(x[base + (size_t)(7 + k) * PLANE]);
                    c[k] = sv;
                    m = fmaxf(m, sv);
                }
                float se = 0.0f;
                #pragma unroll
                for (int k = 0; k < NC; ++k) se += expf(c[k] - m);
                float lse = m + logf(se);
                v[0] = 1.0;
                v[1] = (double)((px - r.tx) * (px - r.tx));
                v[2] = (double)((py - r.ty) * (py - r.ty));
                v[3] = (double)((v2 - r.tw) * (v2 - r.tw));
                v[4] = (double)((v3 - r.th) * (v3 - r.th));
                v[5] = (double)(-logf(pconf));
                v[6] = (double)(lse - c[r.label]);
            }
        }
    }

    // ---- block reduce: 8 waves -> LDS -> thread 0 ----
    #pragma unroll
    for (int k = 0; k < 9; ++k)
        for (int off = 32; off > 0; off >>= 1)
            v[k] += __shfl_down(v[k], off);
    const int lane = tid & 63, wid = tid >> 6;
    if (lane == 0) {
        #pragma unroll
        for (int k = 0; k < 9; ++k) wsum[wid][k] = v[k];
    }
    __syncthreads();
    if (tid == 0) {
        #pragma unroll
        for (int k = 0; k < 9; ++k) {
            double s = 0.0;
            #pragma unroll
            for (int w = 0; w < 8; ++w) s += wsum[w][k];
            acc[k] = s;
        }
    }
}

// ---------------------------------------------------------------------------
// Kernel B: dense noobj BCE over ALL cells (branch-free streaming), block
// partials + last-block-ticket finalize. 360 blocks x 256 threads x 4 float4.
// ---------------------------------------------------------------------------
__global__ __launch_bounds__(256) void conf_fused_k(const float* __restrict__ x,
                                                    const double* __restrict__ acc,
                                                    unsigned int* __restrict__ ticket,
                                                    double* __restrict__ partials,
                                                    float* __restrict__ out) {
    __shared__ double wred[4];
    __shared__ int s_last;
    const int g = blockIdx.x * CONF_THREADS + threadIdx.x;
    double s = 0.0;
    #pragma unroll
    for (int it = 0; it < 4; ++it) {
        int n4 = g + it * CONF_TOTAL;
        int n = n4 * 4;
        int b = n / BATCH_CELLS;
        int rr = n % BATCH_CELLS;
        int a = rr / PLANE;
        int hw = rr % PLANE;
        const float4 v = *reinterpret_cast<const float4*>(
            x + ((size_t)(b * NA + a) * ATTRS + 6) * PLANE + hw);
        s += (double)noobj_term(v.x) + (double)noobj_term(v.y)
           + (double)noobj_term(v.z) + (double)noobj_term(v.w);
    }
    for (int off = 32; off > 0; off >>= 1) s += __shfl_down(s, off);
    const int lane = threadIdx.x & 63, wid = threadIdx.x >> 6;
    if (lane == 0) wred[wid] = s;
    __syncthreads();
    if (threadIdx.x == 0) {
        partials[blockIdx.x] = wred[0] + wred[1] + wred[2] + wred[3];
        __threadfence();
        unsigned int t = atomicAdd(ticket, 1u);
        s_last = (t == CONF_BLOCKS - 1) ? 1 : 0;
    }
    __syncthreads();
    if (!s_last) return;

    // last block: sum partials + combine with acc
    __threadfence();
    double sb = 0.0;
    for (int i = threadIdx.x; i < CONF_BLOCKS; i += CONF_THREADS) sb += partials[i];
    for (int off = 32; off > 0; off >>= 1) sb += __shfl_down(sb, off);
    if (lane == 0) wred[wid] = sb;
    __syncthreads();
    if (threadIdx.x == 0) {
        double dense = wred[0] + wred[1] + wred[2] + wred[3];
        double n_obj = acc[0];
        double noobj_b = dense - acc[7];
        double noobj_c = (double)NCELLS - acc[8];
        double loss = (acc[1] + acc[2] + acc[3] + acc[4]) / n_obj   // x,y,w,h
                    + noobj_b / noobj_c                             // noobj conf
                    + acc[5] / n_obj                                // obj conf
                    + (1.0 / (double)BB) * acc[6] / n_obj;          // cls
        out[0] = (float)loss;
    }
}

extern "C" void kernel_launch(void* const* d_in, const int* in_sizes, int n_in,
                              void* d_out, int out_size, void* d_ws, size_t ws_size,
                              hipStream_t stream) {
    const float* x       = (const float*)d_in[0];
    const float* tgt     = (const float*)d_in[1];
    const float* anchors = (const float*)d_in[2];

    double* acc          = (double*)d_ws;
    unsigned int* ticket = (unsigned int*)((char*)d_ws + TICK_OFF);
    double* partials     = (double*)((char*)d_ws + PART_OFF);

    build_obj_k<<<1, 512, 0, stream>>>(x, tgt, anchors, acc, ticket);
    conf_fused_k<<<CONF_BLOCKS, CONF_THREADS, 0, stream>>>(x, acc, ticket, partials,
                                                           (float*)d_out);
}

// Round 7
// 140.196 us; speedup vs baseline: 1.1035x; 1.1035x over previous
//
#include <hip/hip_runtime.h>
#include <math.h>

#define BB 8
#define NA 5
#define NC 8
#define NH 192
#define NW 192
#define TT 50
#define ATTRS 15
#define THRESH_F 0.6f

#define NTGT (BB * TT)                 // 400
#define PLANE (NH * NW)                // 36864
#define BATCH_CELLS (NA * PLANE)       // 184320
#define NCELLS (BB * BATCH_CELLS)      // 1474560
#define HSZ 4096
#define HEMPTY 0xFFFFFFFFu

#define DENSE_BLOCKS 180
#define GRID_BLOCKS (DENSE_BLOCKS + 1)     // block 180 = builder
#define THREADS 512
#define DENSE_TOTAL (DENSE_BLOCKS * THREADS)   // 92160; N4 = 368640 = 4*92160

// ws layout (all zeroed by 96B memset):
//   double slots 0..8: 0 n_obj, 1 sx, 2 sy, 3 sw, 4 sh, 5 bce_obj, 6 ce,
//                      7 excl_bce, 8 excl_cnt;  slot 9: dense noobj-bce sum
//   u32 ticket @ byte 80
#define TICK_OFF 80

__device__ __forceinline__ float sigmoidf_(float v) {
    return 1.0f / (1.0f + expf(-v));
}

__device__ __forceinline__ float noobj_term(float v) {
    float p = fminf(fmaxf(sigmoidf_(v), 1e-7f), 1.0f - 1e-7f);
    return -log1pf(-p);
}

// coherent read of a cross-XCD-communicated double (device-scope RMW)
__device__ __forceinline__ double ws_read(double* p) {
    return atomicAdd(p, 0.0);
}

__device__ void finalize_(double* ws, float* out) {
    double n_obj   = ws_read(&ws[0]);
    double dense   = ws_read(&ws[9]);
    double noobj_b = dense - ws_read(&ws[7]);
    double noobj_c = (double)NCELLS - ws_read(&ws[8]);
    double loss = (ws_read(&ws[1]) + ws_read(&ws[2]) + ws_read(&ws[3]) + ws_read(&ws[4])) / n_obj
                + noobj_b / noobj_c
                + ws_read(&ws[5]) / n_obj
                + (1.0 / (double)BB) * ws_read(&ws[6]) / n_obj;
    out[0] = (float)loss;
}

struct Rec {
    int cell;      // (a*NH + gj)*NW + gi  (within batch)
    int label;
    float tx, ty, tw, th;
    int valid;
    int pad;
};

// ---------------------------------------------------------------------------
// One kernel, 181 blocks x 512 threads.
//   blocks 0..179 : dense noobj BCE over ALL cells, one double atomicAdd each
//   block  180    : target build + excluded-set hash dedup + per-object losses
//   last ticket   : finalize -> out
// ---------------------------------------------------------------------------
__global__ __launch_bounds__(THREADS) void region_loss_k(const float* __restrict__ x,
                                                         const float* __restrict__ tgt,
                                                         const float* __restrict__ anchors,
                                                         double* __restrict__ ws,
                                                         unsigned int* __restrict__ ticket,
                                                         float* __restrict__ out) {
    __shared__ Rec srecs[NTGT];
    __shared__ unsigned int hset[HSZ];
    __shared__ double wsum[8][9];
    const int tid = threadIdx.x;
    const int bid = blockIdx.x;
    const int lane = tid & 63, wid = tid >> 6;

    if (bid < DENSE_BLOCKS) {
        // ---------------- dense noobj BCE ----------------
        const int g = bid * THREADS + tid;
        double s = 0.0;
        #pragma unroll
        for (int it = 0; it < 4; ++it) {
            int n4 = g + it * DENSE_TOTAL;
            int n = n4 * 4;
            int b = n / BATCH_CELLS;
            int rr = n % BATCH_CELLS;
            int a = rr / PLANE;
            int hw = rr % PLANE;
            const float4 v = *reinterpret_cast<const float4*>(
                x + ((size_t)(b * NA + a) * ATTRS + 6) * PLANE + hw);
            s += (double)noobj_term(v.x) + (double)noobj_term(v.y)
               + (double)noobj_term(v.z) + (double)noobj_term(v.w);
        }
        for (int off = 32; off > 0; off >>= 1) s += __shfl_down(s, off);
        if (lane == 0) wsum[wid][0] = s;
        __syncthreads();
        if (tid == 0) {
            double bsum = 0.0;
            #pragma unroll
            for (int w = 0; w < 8; ++w) bsum += wsum[w][0];
            atomicAdd(&ws[9], bsum);
            __threadfence();
            unsigned int t = atomicAdd(ticket, 1u);
            if (t == GRID_BLOCKS - 1) finalize_(ws, out);
        }
        return;
    }

    // ---------------- builder block ----------------
    for (int i = tid; i < HSZ; i += THREADS) hset[i] = HEMPTY;
    __syncthreads();

    double corr_b = 0.0, corr_c = 0.0;

    // phase 1: build + excluded-set dedup
    if (tid < NTGT) {
        const int b = tid / TT;
        const float* p = tgt + (size_t)tid * 5;
        float lab = p[0], cx = p[1], cy = p[2], cw = p[3], ch = p[4];
        int valid = ((lab + cx + cy + cw + ch) != 0.0f) ? 1 : 0;
        float gx = cx * NW, gy = cy * NH, gw = cw * NW, gh = ch * NH;
        int gi = min(max((int)floorf(gx), 0), NW - 1);
        int gj = min(max((int)floorf(gy), 0), NH - 1);
        float ious[NA];
        float aw[NA], ah[NA];
        int best = 0; float bi = -1.0f;
        #pragma unroll
        for (int a = 0; a < NA; ++a) {
            aw[a] = anchors[2 * a];
            ah[a] = anchors[2 * a + 1];
            float inter = fminf(gw, aw[a]) * fminf(gh, ah[a]);
            float un = gw * gh + aw[a] * ah[a] - inter;
            float iou = inter / un;
            ious[a] = iou;
            if (iou > bi) { bi = iou; best = a; }   // first-max (jnp.argmax)
        }
        if (valid) {
            // excluded set = {iou>thresh cells} U {best cell}; dedup via LDS hash
            #pragma unroll
            for (int a = 0; a <= NA; ++a) {
                int aa; bool doit;
                if (a < NA) { aa = a; doit = (ious[a] > THRESH_F); }
                else        { aa = best; doit = true; }
                if (!doit) continue;
                unsigned int key = (unsigned int)((b * NA + aa) * PLANE + gj * NW + gi);
                unsigned int h = (key * 2654435761u) & (HSZ - 1);
                while (true) {
                    unsigned int old = atomicCAS(&hset[h], HEMPTY, key);
                    if (old == HEMPTY) {   // new cell -> contribute correction
                        int cb = key / BATCH_CELLS;
                        int cr = key % BATCH_CELLS;
                        int ca = cr / PLANE;
                        int chw = cr % PLANE;
                        float v = x[((size_t)(cb * NA + ca) * ATTRS + 6) * PLANE + chw];
                        corr_b += (double)noobj_term(v);
                        corr_c += 1.0;
                        break;
                    }
                    if (old == key) break;  // duplicate
                    h = (h + 1) & (HSZ - 1);
                }
            }
        }
        Rec r;
        r.valid = valid;
        r.cell = (best * NH + gj) * NW + gi;
        r.label = (int)lab;
        r.tx = gx - floorf(gx);
        r.ty = gy - floorf(gy);
        r.tw = logf(gw / aw[best] + 1e-16f);
        r.th = logf(gh / ah[best] + 1e-16f);
        srecs[tid] = r;
    }
    __syncthreads();

    // phase 2: per-object losses
    double v[9];
    #pragma unroll
    for (int k = 0; k < 9; ++k) v[k] = 0.0;
    v[7] = corr_b;
    v[8] = corr_c;

    if (tid < NTGT) {
        Rec r = srecs[tid];
        if (r.valid) {
            const int b = tid / TT, t = tid % TT;
            bool superseded = false;
            for (int t2 = t + 1; t2 < TT; ++t2) {
                Rec r2 = srecs[b * TT + t2];
                if (r2.valid && r2.cell == r.cell) { superseded = true; break; }
            }
            if (!superseded) {
                int a  = r.cell / PLANE;
                int hw = r.cell % PLANE;
                size_t base = ((size_t)(b * NA + a) * ATTRS) * PLANE + hw;
                float v0 = x[base + 0 * PLANE];
                float v1 = x[base + 1 * PLANE];
                float v2 = x[base + 2 * PLANE];
                float v3 = x[base + 3 * PLANE];
                float v6 = x[base + 6 * PLANE];
                float px = sigmoidf_(v0);
                float py = sigmoidf_(v1);
                float pconf = fminf(fmaxf(sigmoidf_(v6), 1e-7f), 1.0f - 1e-7f);
                float c[NC];
                float m = -INFINITY;
                #pragma unroll
                for (int k = 0; k < NC; ++k) {
                    float sv = sigmoidf_(x[base + (size_t)(7 + k) * PLANE]);
                    c[k] = sv;
                    m = fmaxf(m, sv);
                }
                float se = 0.0f;
                #pragma unroll
                for (int k = 0; k < NC; ++k) se += expf(c[k] - m);
                float lse = m + logf(se);
                v[0] = 1.0;
                v[1] = (double)((px - r.tx) * (px - r.tx));
                v[2] = (double)((py - r.ty) * (py - r.ty));
                v[3] = (double)((v2 - r.tw) * (v2 - r.tw));
                v[4] = (double)((v3 - r.th) * (v3 - r.th));
                v[5] = (double)(-logf(pconf));
                v[6] = (double)(lse - c[r.label]);
            }
        }
    }

    // block reduce: 8 waves -> LDS -> thread 0 -> device-scope atomics
    #pragma unroll
    for (int k = 0; k < 9; ++k)
        for (int off = 32; off > 0; off >>= 1)
            v[k] += __shfl_down(v[k], off);
    if (lane == 0) {
        #pragma unroll
        for (int k = 0; k < 9; ++k) wsum[wid][k] = v[k];
    }
    __syncthreads();
    if (tid == 0) {
        #pragma unroll
        for (int k = 0; k < 9; ++k) {
            double s = 0.0;
            #pragma unroll
            for (int w = 0; w < 8; ++w) s += wsum[w][k];
            atomicAdd(&ws[k], s);     // ws zeroed by memset; atomic = XCD-coherent
        }
        __threadfence();
        unsigned int t = atomicAdd(ticket, 1u);
        if (t == GRID_BLOCKS - 1) finalize_(ws, out);
    }
}

extern "C" void kernel_launch(void* const* d_in, const int* in_sizes, int n_in,
                              void* d_out, int out_size, void* d_ws, size_t ws_size,
                              hipStream_t stream) {
    const float* x       = (const float*)d_in[0];
    const float* tgt     = (const float*)d_in[1];
    const float* anchors = (const float*)d_in[2];

    double* ws           = (double*)d_ws;
    unsigned int* ticket = (unsigned int*)((char*)d_ws + TICK_OFF);

    // zero acc slots 0..9 + ticket (d_ws is 0xAA-poisoned before every call)
    hipMemsetAsync(d_ws, 0, 96, stream);

    region_loss_k<<<GRID_BLOCKS, THREADS, 0, stream>>>(x, tgt, anchors, ws, ticket,
                                                       (float*)d_out);
}